// Round 9
// baseline (313.760 us; speedup 1.0000x reference)
//
#include <hip/hip_runtime.h>
#include <hip/hip_bf16.h>

// Problem constants (fixed by setup_inputs)
constexpr int B = 4, Q = 100, C = 40, Cp1 = 41, HW = 65536;
constexpr int NPIX = B * HW;          // 262144

// A-part: 512 blocks, 256 thr, 2 px/thread (float2), 5-plane load batches
constexpr int ATHR = 256, APX = 2;
constexpr int ABLKS = NPIX / (ATHR * APX);   // 512
constexpr int ASLOT = HW / (ATHR * APX);     // 128 A-blocks per batch image
constexpr int QU = 5;                         // 20 groups of 5 planes

// B-part: 8 chunks -> 3200 blocks, 256 thr, hist 40 KB -> 4 blocks/CU
constexpr int BCH = 8;
constexpr int BCPX = HW / BCH;               // 8192 px/block
constexpr int BIT = BCPX / (ATHR * 4);       // 8 iters

constexpr int GRID = ABLKS + B * Q * BCH;    // 3712

// Workspace layout (4-byte words) — verified R4 layout
//  [0, 16000)      counts  u32 [B][Q][C]
//  [16000, 16160)  tsum    u32 [B][C]
//  [16160, 32160)  inter   f32 [B][Q][C]
//  [32160, 32560)  src_sum f32 [B][Q]
//  [32560]         ce_sum  f32
//  [32561]         n_valid u32
constexpr int WS_WORDS = 32562;

__global__ void kZ(unsigned* __restrict__ ws, int n) {
    int i = blockIdx.x * blockDim.x + threadIdx.x;
    for (; i < n; i += gridDim.x * blockDim.x) ws[i] = 0u;
}

// ONE kernel, two independent phases selected by blockIdx (uniform branch).
// R9 change vs R8: B-part histogram update is a fire-and-forget LDS atomic
// (ds_add_f32, no return) instead of a read-modify-write — removes the
// dependent ds_read->waitcnt->add->ds_write chain that serialized on
// possibly-aliasing data-dependent addresses. Sigmoid via v_rcp_f32.
__global__ __launch_bounds__(256, 4) void kBig(const float* __restrict__ masks,
                                               const int* __restrict__ targets,
                                               unsigned* __restrict__ counts,
                                               unsigned* __restrict__ tsum,
                                               float* __restrict__ ce_sum,
                                               unsigned* __restrict__ n_valid,
                                               float* __restrict__ inter,
                                               float* __restrict__ src_sum) {
    __shared__ float hist[C][ATHR];   // exactly 40 KB -> 4 blocks/CU
    int tid = threadIdx.x;
    int blk = blockIdx.x;

    if (blk < ABLKS) {
        // ---------- A-part: pixel-major ----------
        unsigned* ts_local = (unsigned*)&hist[0][0];   // alias: words 0..39
        float*    cred     = &hist[0][64];             // words 64..67
        unsigned* vred     = (unsigned*)&hist[0][72];  // words 72..75

        int b = blk / ASLOT;
        int hw = (blk % ASLOT) * (ATHR * APX) + tid * APX;
        const float* mp = masks + (size_t)b * Q * HW + hw;
        int2 tg = *(const int2*)(targets + (size_t)b * HW + hw);
        int tgs[2] = {tg.x, tg.y};

        float m[2] = {-INFINITY, -INFINITY}, s[2] = {0.f, 0.f}, xt[2] = {0.f, 0.f};
        int amax[2] = {0, 0};

        for (int qq = 0; qq < Q; qq += QU) {
            float2 vv[QU];
            #pragma unroll
            for (int u = 0; u < QU; ++u)
                vv[u] = *(const float2*)(mp + (size_t)(qq + u) * HW);
            #pragma unroll
            for (int u = 0; u < QU; ++u) {
                int q = qq + u;
                float v[2] = {vv[u].x, vv[u].y};
                #pragma unroll
                for (int j = 0; j < 2; ++j) {
                    s[j] += __expf(v[j]);                    // |v|<=~6: f32-safe
                    amax[j] = (v[j] > m[j]) ? q : amax[j];   // strict >: first max
                    m[j] = fmaxf(m[j], v[j]);
                    xt[j] = (q == tgs[j]) ? v[j] : xt[j];
                }
            }
        }

        if (tid < C) ts_local[tid] = 0u;
        __syncthreads();

        float ce = 0.f;
        unsigned nv = 0;
        #pragma unroll
        for (int j = 0; j < 2; ++j) {
            if (tgs[j] != 255) {                             // valid; in [0,40)
                ce += __logf(s[j]) - xt[j];
                nv++;
                atomicAdd(&counts[((size_t)b * Q + amax[j]) * C + tgs[j]], 1u);
                atomicAdd(&ts_local[tgs[j]], 1u);
            }
        }
        for (int off = 32; off; off >>= 1) {
            ce += __shfl_xor(ce, off);
            nv += __shfl_xor(nv, off);
        }
        int lane = tid & 63, wave = tid >> 6;
        if (lane == 0) { cred[wave] = ce; vred[wave] = nv; }
        __syncthreads();   // covers ts_local atomics too
        if (tid == 0) {
            atomicAdd(ce_sum, cred[0] + cred[1] + cred[2] + cred[3]);
            atomicAdd(n_valid, vred[0] + vred[1] + vred[2] + vred[3]);
        }
        if (tid < C) {
            unsigned t = ts_local[tid];
            if (t) atomicAdd(&tsum[b * C + tid], t);
        }
    } else {
        // ---------- B-part: (b,q)-major ----------
        int r = blk - ABLKS;             // 0..3199
        int bq = r >> 3;
        int chunk = r & 7;
        int b = bq / Q;
        const float* mp = masks + (size_t)bq * HW + chunk * BCPX;
        const int* tp = targets + (size_t)b * HW + chunk * BCPX;

        #pragma unroll
        for (int c = 0; c < C; ++c) hist[c][tid] = 0.f;   // own column only
        // no barrier needed: each thread only ds_add's its own column below

        float sacc = 0.f;
        #pragma unroll 2
        for (int it = 0; it < BIT; ++it) {                 // 8 iters * 1024 px
            int off = it * (ATHR * 4) + tid * 4;
            float4 x = *(const float4*)(mp + off);
            int4 tg = *(const int4*)(tp + off);
            float xs[4] = {x.x, x.y, x.z, x.w};
            int cs[4] = {tg.x, tg.y, tg.z, tg.w};
            #pragma unroll
            for (int j = 0; j < 4; ++j) {
                float sig = __builtin_amdgcn_rcpf(1.f + __expf(-xs[j]));
                sacc += sig;
                if ((unsigned)cs[j] < (unsigned)C)
                    atomicAdd(&hist[cs[j]][tid], sig);     // ds_add_f32, no return
            }
        }

        for (int off = 32; off; off >>= 1) sacc += __shfl_xor(sacc, off);
        int lane = tid & 63, wave = tid >> 6;
        if (lane == 0) atomicAdd(&src_sum[bq], sacc);

        __syncthreads();   // LDS atomics drained before cross-column reads
        // wave w reduces 10 classes
        for (int c = wave * 10; c < wave * 10 + 10; ++c) {
            float h = hist[c][lane] + hist[c][lane + 64] + hist[c][lane + 128] + hist[c][lane + 192];
            for (int off = 32; off; off >>= 1) h += __shfl_xor(h, off);
            if (lane == 0) atomicAdd(&inter[(size_t)bq * C + c], h);
        }
    }
}

// Kernel C: finalize. Single block. f32 scalar out. (Verified R4.)
__global__ __launch_bounds__(512) void kC(const float* __restrict__ logits,
                                          const unsigned* __restrict__ counts,
                                          const unsigned* __restrict__ tsum,
                                          const float* __restrict__ inter,
                                          const float* __restrict__ src_sum,
                                          const float* __restrict__ ce_sum,
                                          const unsigned* __restrict__ n_valid,
                                          float* __restrict__ out) {
    int tid = threadIdx.x;
    __shared__ float dice_sum[C];
    __shared__ float wred[8];
    __shared__ float s_lce;
    if (tid < C) dice_sum[tid] = 0.f;

    float ce_acc = 0.f;
    for (int i = tid; i < B * Q; i += 512) {
        const unsigned* cnt = counts + (size_t)i * C;
        unsigned best = 0;
        int tc = C;
        #pragma unroll
        for (int c = 0; c < C; ++c) {
            unsigned v = cnt[c];
            if (v > best) { best = v; tc = c; }
        }
        if (tc != C) {
            const float* lg = logits + (size_t)i * Cp1;
            float mm = -INFINITY, xt = 0.f;
            #pragma unroll
            for (int c = 0; c < Cp1; ++c) {
                float v = lg[c];
                mm = fmaxf(mm, v);
                if (c == tc) xt = v;
            }
            float ss = 0.f;
            #pragma unroll
            for (int c = 0; c < Cp1; ++c) ss += __expf(lg[c] - mm);
            float nll = mm + __logf(ss) - xt;
            float p = __expf(-nll);
            float om = 1.f - p;
            ce_acc += om * om * nll;
        }
    }
    for (int off = 32; off; off >>= 1) ce_acc += __shfl_xor(ce_acc, off);
    if ((tid & 63) == 0) wred[tid >> 6] = ce_acc;
    __syncthreads();
    if (tid == 0) {
        float t = 0.f;
        for (int w = 0; w < 8; ++w) t += wred[w];
        s_lce = t;
    }

    for (int i = tid; i < B * Q * C; i += 512) {
        int bq = i / C, c = i - bq * C;
        float denom = src_sum[bq] + (float)tsum[(bq / Q) * C + c] + 1e-8f;
        atomicAdd(&dice_sum[c], 2.f * inter[i] / denom);
    }
    __syncthreads();

    if (tid == 0) {
        float dl = 0.f;
        for (int c = 0; c < C; ++c) {
            unsigned ts = tsum[c] + tsum[C + c] + tsum[2 * C + c] + tsum[3 * C + c];
            if (ts > 0) dl += 1.f - dice_sum[c] * (1.f / (B * Q));
        }
        dl *= (1.f / C);
        float ce_mask = ce_sum[0] / fmaxf((float)n_valid[0], 1.f);
        float lce = s_lce * (1.f / (B * Q));
        out[0] = 2.f * lce + 5.f * ce_mask + 5.f * dl;
    }
}

extern "C" void kernel_launch(void* const* d_in, const int* in_sizes, int n_in,
                              void* d_out, int out_size, void* d_ws, size_t ws_size,
                              hipStream_t stream) {
    const float* logits  = (const float*)d_in[0];   // [B,Q,41] f32
    const float* masks   = (const float*)d_in[1];   // [B,Q,H,W] f32
    const int*   targets = (const int*)d_in[2];     // [B,H,W] int32
    float* out = (float*)d_out;                     // f32 scalar

    unsigned* ws      = (unsigned*)d_ws;
    unsigned* counts  = ws;                         // 16000 u32
    unsigned* tsum    = ws + 16000;                 // 160 u32
    float*    inter   = (float*)(ws + 16160);       // 16000 f32
    float*    src_sum = (float*)(ws + 32160);       // 400 f32
    float*    ce_sum  = (float*)(ws + 32560);       // 1 f32
    unsigned* n_valid = ws + 32561;                 // 1 u32

    kZ<<<64, 256, 0, stream>>>(ws, WS_WORDS);
    kBig<<<GRID, ATHR, 0, stream>>>(masks, targets, counts, tsum, ce_sum, n_valid,
                                    inter, src_sum);
    kC<<<1, 512, 0, stream>>>(logits, counts, tsum, inter, src_sum, ce_sum, n_valid, out);
}

// Round 10
// 265.782 us; speedup vs baseline: 1.1805x; 1.1805x over previous
//
#include <hip/hip_runtime.h>
#include <hip/hip_bf16.h>

// Problem constants (fixed by setup_inputs)
constexpr int B = 4, Q = 100, C = 40, Cp1 = 41, HW = 65536;
constexpr int NPIX = B * HW;          // 262144

// A-part: 512 blocks, 256 thr, 2 px/thread (float2), 5-plane load batches
constexpr int ATHR = 256, APX = 2;
constexpr int ABLKS = NPIX / (ATHR * APX);   // 512
constexpr int ASLOT = HW / (ATHR * APX);     // 128 A-blocks per batch image
constexpr int QU = 5;                         // 20 groups of 5 planes

// B-part: 8 chunks -> 3200 blocks, 256 thr, register histogram (no LDS)
constexpr int BCH = 8;
constexpr int BCPX = HW / BCH;               // 8192 px/block
constexpr int BIT = BCPX / (ATHR * 4);       // 8 iters

constexpr int GRID = ABLKS + B * Q * BCH;    // 3712

// Workspace layout (4-byte words) — verified R4 layout
//  [0, 16000)      counts  u32 [B][Q][C]
//  [16000, 16160)  tsum    u32 [B][C]
//  [16160, 32160)  inter   f32 [B][Q][C]
//  [32160, 32560)  src_sum f32 [B][Q]
//  [32560]         ce_sum  f32
//  [32561]         n_valid u32
constexpr int WS_WORDS = 32562;

__global__ void kZ(unsigned* __restrict__ ws, int n) {
    int i = blockIdx.x * blockDim.x + threadIdx.x;
    for (; i < n; i += gridDim.x * blockDim.x) ws[i] = 0u;
}

// ONE kernel, two independent phases selected by blockIdx (uniform branch).
// R10 change: B-part histogram lives in 40 per-thread VGPRs with STATIC
// indexing (unrolled compare-select over classes) — zero per-element LDS.
// R9 proved LDS atomics are lane-serialized (~256 cyc/wave-op) and R4-R8's
// rmw chains were the hidden ~80 us; this replaces both with ~22 us of VALU.
__global__ __launch_bounds__(256) void kBig(const float* __restrict__ masks,
                                            const int* __restrict__ targets,
                                            unsigned* __restrict__ counts,
                                            unsigned* __restrict__ tsum,
                                            float* __restrict__ ce_sum,
                                            unsigned* __restrict__ n_valid,
                                            float* __restrict__ inter,
                                            float* __restrict__ src_sum) {
    __shared__ float smem[4 * C];     // B: per-wave class sums. A: aliased tiny arrays.
    int tid = threadIdx.x;
    int blk = blockIdx.x;
    int lane = tid & 63, wave = tid >> 6;

    if (blk < ABLKS) {
        // ---------- A-part: pixel-major (unchanged from R8, verified) ----------
        unsigned* ts_local = (unsigned*)&smem[0];      // words 0..39
        float*    cred     = &smem[64];                // words 64..67
        unsigned* vred     = (unsigned*)&smem[72];     // words 72..75

        int b = blk / ASLOT;
        int hw = (blk % ASLOT) * (ATHR * APX) + tid * APX;
        const float* mp = masks + (size_t)b * Q * HW + hw;
        int2 tg = *(const int2*)(targets + (size_t)b * HW + hw);
        int tgs[2] = {tg.x, tg.y};

        float m[2] = {-INFINITY, -INFINITY}, s[2] = {0.f, 0.f}, xt[2] = {0.f, 0.f};
        int amax[2] = {0, 0};

        for (int qq = 0; qq < Q; qq += QU) {
            float2 vv[QU];
            #pragma unroll
            for (int u = 0; u < QU; ++u)
                vv[u] = *(const float2*)(mp + (size_t)(qq + u) * HW);
            #pragma unroll
            for (int u = 0; u < QU; ++u) {
                int q = qq + u;
                float v[2] = {vv[u].x, vv[u].y};
                #pragma unroll
                for (int j = 0; j < 2; ++j) {
                    s[j] += __expf(v[j]);                    // |v|<=~6: f32-safe
                    amax[j] = (v[j] > m[j]) ? q : amax[j];   // strict >: first max
                    m[j] = fmaxf(m[j], v[j]);
                    xt[j] = (q == tgs[j]) ? v[j] : xt[j];
                }
            }
        }

        if (tid < C) ts_local[tid] = 0u;
        __syncthreads();

        float ce = 0.f;
        unsigned nv = 0;
        #pragma unroll
        for (int j = 0; j < 2; ++j) {
            if (tgs[j] != 255) {                             // valid; in [0,40)
                ce += __logf(s[j]) - xt[j];
                nv++;
                atomicAdd(&counts[((size_t)b * Q + amax[j]) * C + tgs[j]], 1u);
                atomicAdd(&ts_local[tgs[j]], 1u);
            }
        }
        for (int off = 32; off; off >>= 1) {
            ce += __shfl_xor(ce, off);
            nv += __shfl_xor(nv, off);
        }
        if (lane == 0) { cred[wave] = ce; vred[wave] = nv; }
        __syncthreads();   // covers ts_local atomics too
        if (tid == 0) {
            atomicAdd(ce_sum, cred[0] + cred[1] + cred[2] + cred[3]);
            atomicAdd(n_valid, vred[0] + vred[1] + vred[2] + vred[3]);
        }
        if (tid < C) {
            unsigned t = ts_local[tid];
            if (t) atomicAdd(&tsum[b * C + tid], t);
        }
    } else {
        // ---------- B-part: (b,q)-major, register histogram ----------
        int r = blk - ABLKS;             // 0..3199
        int bq = r >> 3;
        int chunk = r & 7;
        int b = bq / Q;
        const float* mp = masks + (size_t)bq * HW + chunk * BCPX;
        const int* tp = targets + (size_t)b * HW + chunk * BCPX;

        float acc[C];
        #pragma unroll
        for (int k = 0; k < C; ++k) acc[k] = 0.f;

        float sacc = 0.f;
        for (int it = 0; it < BIT; ++it) {                 // 8 iters * 1024 px
            int off = it * (ATHR * 4) + tid * 4;
            float4 x = *(const float4*)(mp + off);
            int4 tg = *(const int4*)(tp + off);
            float xs[4] = {x.x, x.y, x.z, x.w};
            int cs[4] = {tg.x, tg.y, tg.z, tg.w};
            float sg[4];
            #pragma unroll
            for (int j = 0; j < 4; ++j) {
                sg[j] = __builtin_amdgcn_rcpf(1.f + __expf(-xs[j]));
                sacc += sg[j];
            }
            #pragma unroll
            for (int k = 0; k < C; ++k) {
                float add = 0.f;
                #pragma unroll
                for (int j = 0; j < 4; ++j)
                    add += (cs[j] == k) ? sg[j] : 0.f;     // 255 matches nothing
                acc[k] += add;
            }
        }

        // src_sum: wave reduce + atomic
        float ss = sacc;
        for (int off = 32; off; off >>= 1) ss += __shfl_xor(ss, off);
        if (lane == 0) atomicAdd(&src_sum[bq], ss);

        // class sums: shuffle-reduce each acc, stage per wave, combine
        #pragma unroll
        for (int k = 0; k < C; ++k) {
            float a = acc[k];
            for (int off = 32; off; off >>= 1) a += __shfl_xor(a, off);
            if (lane == 0) smem[wave * C + k] = a;
        }
        __syncthreads();
        if (tid < C) {
            float t = smem[tid] + smem[C + tid] + smem[2 * C + tid] + smem[3 * C + tid];
            atomicAdd(&inter[(size_t)bq * C + tid], t);
        }
    }
}

// Kernel C: finalize. Single block. f32 scalar out. (Verified R4.)
__global__ __launch_bounds__(512) void kC(const float* __restrict__ logits,
                                          const unsigned* __restrict__ counts,
                                          const unsigned* __restrict__ tsum,
                                          const float* __restrict__ inter,
                                          const float* __restrict__ src_sum,
                                          const float* __restrict__ ce_sum,
                                          const unsigned* __restrict__ n_valid,
                                          float* __restrict__ out) {
    int tid = threadIdx.x;
    __shared__ float dice_sum[C];
    __shared__ float wred[8];
    __shared__ float s_lce;
    if (tid < C) dice_sum[tid] = 0.f;

    float ce_acc = 0.f;
    for (int i = tid; i < B * Q; i += 512) {
        const unsigned* cnt = counts + (size_t)i * C;
        unsigned best = 0;
        int tc = C;
        #pragma unroll
        for (int c = 0; c < C; ++c) {
            unsigned v = cnt[c];
            if (v > best) { best = v; tc = c; }
        }
        if (tc != C) {
            const float* lg = logits + (size_t)i * Cp1;
            float mm = -INFINITY, xt = 0.f;
            #pragma unroll
            for (int c = 0; c < Cp1; ++c) {
                float v = lg[c];
                mm = fmaxf(mm, v);
                if (c == tc) xt = v;
            }
            float ss = 0.f;
            #pragma unroll
            for (int c = 0; c < Cp1; ++c) ss += __expf(lg[c] - mm);
            float nll = mm + __logf(ss) - xt;
            float p = __expf(-nll);
            float om = 1.f - p;
            ce_acc += om * om * nll;
        }
    }
    for (int off = 32; off; off >>= 1) ce_acc += __shfl_xor(ce_acc, off);
    if ((tid & 63) == 0) wred[tid >> 6] = ce_acc;
    __syncthreads();
    if (tid == 0) {
        float t = 0.f;
        for (int w = 0; w < 8; ++w) t += wred[w];
        s_lce = t;
    }

    for (int i = tid; i < B * Q * C; i += 512) {
        int bq = i / C, c = i - bq * C;
        float denom = src_sum[bq] + (float)tsum[(bq / Q) * C + c] + 1e-8f;
        atomicAdd(&dice_sum[c], 2.f * inter[i] / denom);
    }
    __syncthreads();

    if (tid == 0) {
        float dl = 0.f;
        for (int c = 0; c < C; ++c) {
            unsigned ts = tsum[c] + tsum[C + c] + tsum[2 * C + c] + tsum[3 * C + c];
            if (ts > 0) dl += 1.f - dice_sum[c] * (1.f / (B * Q));
        }
        dl *= (1.f / C);
        float ce_mask = ce_sum[0] / fmaxf((float)n_valid[0], 1.f);
        float lce = s_lce * (1.f / (B * Q));
        out[0] = 2.f * lce + 5.f * ce_mask + 5.f * dl;
    }
}

extern "C" void kernel_launch(void* const* d_in, const int* in_sizes, int n_in,
                              void* d_out, int out_size, void* d_ws, size_t ws_size,
                              hipStream_t stream) {
    const float* logits  = (const float*)d_in[0];   // [B,Q,41] f32
    const float* masks   = (const float*)d_in[1];   // [B,Q,H,W] f32
    const int*   targets = (const int*)d_in[2];     // [B,H,W] int32
    float* out = (float*)d_out;                     // f32 scalar

    unsigned* ws      = (unsigned*)d_ws;
    unsigned* counts  = ws;                         // 16000 u32
    unsigned* tsum    = ws + 16000;                 // 160 u32
    float*    inter   = (float*)(ws + 16160);       // 16000 f32
    float*    src_sum = (float*)(ws + 32160);       // 400 f32
    float*    ce_sum  = (float*)(ws + 32560);       // 1 f32
    unsigned* n_valid = ws + 32561;                 // 1 u32

    kZ<<<64, 256, 0, stream>>>(ws, WS_WORDS);
    kBig<<<GRID, ATHR, 0, stream>>>(masks, targets, counts, tsum, ce_sum, n_valid,
                                    inter, src_sum);
    kC<<<1, 512, 0, stream>>>(logits, counts, tsum, inter, src_sum, ce_sum, n_valid, out);
}

// Round 11
// 225.320 us; speedup vs baseline: 1.3925x; 1.1796x over previous
//
#include <hip/hip_runtime.h>
#include <hip/hip_bf16.h>

// Problem constants (fixed by setup_inputs)
constexpr int B = 4, Q = 100, C = 40, Cp1 = 41, HW = 65536;
constexpr int NPIX = B * HW;          // 262144

// B-part (MFMA one-hot GEMM): 7 q-tiles x 4 b = 28 rows, 128 K-segments of 512
constexpr int QT = 7;
constexpr int ROWS = B * QT;          // 28
constexpr int SEGS = 128;
constexpr int KSEG = HW / SEGS;       // 512
constexpr int BWAVES = ROWS * SEGS;   // 3584
constexpr int BBLK = BWAVES / 4;      // 896 blocks (4 waves each)

// A-part: 512 blocks, 256 thr, 2 px/thread (float2), 5-plane load batches
constexpr int ATHR = 256, APX = 2;
constexpr int ABLKS = NPIX / (ATHR * APX);   // 512
constexpr int ASLOT = HW / (ATHR * APX);     // 128
constexpr int QU = 5;

constexpr int GRID = BBLK + ABLKS;    // 1408

// Workspace layout (4-byte words):
//  [0, 16000)        counts    u32 [B][Q][C]
//  [16000, 16160)    tsum      u32 [B][C]
//  [16160]           ce_sum    f32
//  [16161]           n_valid   u32
//  [16162, 32562)    inter_ext f32 [B*Q][41]   (col 40 = ignored-pixel sig sum)
constexpr int WS_WORDS = 32562;

typedef __attribute__((ext_vector_type(8))) short short8;   // 8 bf16
typedef __attribute__((ext_vector_type(4))) float f32x4;

__device__ __forceinline__ short f2bf(float f) {            // RNE f32->bf16
    unsigned u = __float_as_uint(f);
    u += 0x7FFF + ((u >> 16) & 1);
    return (short)(u >> 16);
}

__global__ void kZ(unsigned* __restrict__ ws, int n) {
    int i = blockIdx.x * blockDim.x + threadIdx.x;
    for (; i < n; i += gridDim.x * blockDim.x) ws[i] = 0u;
}

// ONE kernel, two independent phases (uniform branch on blockIdx).
// B-part: inter = sigmoid(masks) x onehot(targets) as MFMA GEMM.
//   A-frag: A[m=lane&15][k=quad*8+j]; B-frag: B[k=quad*8+j][n=lane&15];
//   D: col=lane&15, row=quad*4+reg  (guide Sec3, HW-verified layouts).
// A-part: pixel-major argmax/LSE/counts (unchanged, verified R8/R10).
__global__ __launch_bounds__(256) void kBig(const float* __restrict__ masks,
                                            const int* __restrict__ targets,
                                            unsigned* __restrict__ counts,
                                            unsigned* __restrict__ tsum,
                                            float* __restrict__ ce_sum,
                                            unsigned* __restrict__ n_valid,
                                            float* __restrict__ inter_ext) {
    __shared__ float smem[4 * C];
    int tid = threadIdx.x;
    int blk = blockIdx.x;
    int lane = tid & 63, wave = tid >> 6;

    if (blk < BBLK) {
        // ---------- B-part: MFMA one-hot GEMM ----------
        int w = blk * 4 + wave;          // 0..3583
        int row = w >> 7;                // /SEGS
        int seg = w & (SEGS - 1);
        int b = row / QT, qt = row - b * QT;
        int q0 = qt * 16;
        int k0 = seg * KSEG;
        int m = lane & 15, quad = lane >> 4;
        int qa = q0 + m; if (qa > 99) qa = 0;        // clamp (garbage rows unused)
        const float* ap = masks + ((size_t)b * Q + qa) * HW + k0 + quad * 8;
        const int*   tp = targets + (size_t)b * HW + k0 + quad * 8;
        int cv0 = m, cv1 = 16 + m;
        int cv2 = (m == 8) ? 255 : 32 + m;           // col 40 <- ignored pixels

        f32x4 acc0 = {0.f, 0.f, 0.f, 0.f};
        f32x4 acc1 = {0.f, 0.f, 0.f, 0.f};
        f32x4 acc2 = {0.f, 0.f, 0.f, 0.f};

        #pragma unroll 2
        for (int step = 0; step < KSEG / 32; ++step) {   // 16 steps
            int k = step * 32;
            float4 x0 = *(const float4*)(ap + k);
            float4 x1 = *(const float4*)(ap + k + 4);
            int4 t0 = *(const int4*)(tp + k);
            int4 t1 = *(const int4*)(tp + k + 4);
            float xs[8] = {x0.x, x0.y, x0.z, x0.w, x1.x, x1.y, x1.z, x1.w};
            int tss[8] = {t0.x, t0.y, t0.z, t0.w, t1.x, t1.y, t1.z, t1.w};
            short8 av, b0, b1, b2;
            #pragma unroll
            for (int j = 0; j < 8; ++j) {
                float sg = __builtin_amdgcn_rcpf(1.f + __expf(-xs[j]));
                av[j] = f2bf(sg);
                b0[j] = (tss[j] == cv0) ? (short)0x3F80 : (short)0;
                b1[j] = (tss[j] == cv1) ? (short)0x3F80 : (short)0;
                b2[j] = (tss[j] == cv2) ? (short)0x3F80 : (short)0;
            }
            acc0 = __builtin_amdgcn_mfma_f32_16x16x32_bf16(av, b0, acc0, 0, 0, 0);
            acc1 = __builtin_amdgcn_mfma_f32_16x16x32_bf16(av, b1, acc1, 0, 0, 0);
            acc2 = __builtin_amdgcn_mfma_f32_16x16x32_bf16(av, b2, acc2, 0, 0, 0);
        }

        // epilogue: D row = quad*4+reg, col = m (+ tile offset)
        int bq0 = b * Q + q0;
        #pragma unroll
        for (int reg = 0; reg < 4; ++reg) {
            int q = q0 + quad * 4 + reg;
            if (q < 100) {
                size_t base = (size_t)(b * Q + q) * Cp1;
                atomicAdd(&inter_ext[base + m], acc0[reg]);
                atomicAdd(&inter_ext[base + 16 + m], acc1[reg]);
                if (m <= 8) atomicAdd(&inter_ext[base + 32 + m], acc2[reg]);
            }
        }
    } else {
        // ---------- A-part: pixel-major (unchanged, verified) ----------
        unsigned* ts_local = (unsigned*)&smem[0];
        float*    cred     = &smem[64];
        unsigned* vred     = (unsigned*)&smem[72];

        int ablk = blk - BBLK;
        int b = ablk / ASLOT;
        int hw = (ablk % ASLOT) * (ATHR * APX) + tid * APX;
        const float* mp = masks + (size_t)b * Q * HW + hw;
        int2 tg = *(const int2*)(targets + (size_t)b * HW + hw);
        int tgs[2] = {tg.x, tg.y};

        float m2[2] = {-INFINITY, -INFINITY}, s[2] = {0.f, 0.f}, xt[2] = {0.f, 0.f};
        int amax[2] = {0, 0};

        for (int qq = 0; qq < Q; qq += QU) {
            float2 vv[QU];
            #pragma unroll
            for (int u = 0; u < QU; ++u)
                vv[u] = *(const float2*)(mp + (size_t)(qq + u) * HW);
            #pragma unroll
            for (int u = 0; u < QU; ++u) {
                int q = qq + u;
                float v[2] = {vv[u].x, vv[u].y};
                #pragma unroll
                for (int j = 0; j < 2; ++j) {
                    s[j] += __expf(v[j]);                      // |v|<=~6: f32-safe
                    amax[j] = (v[j] > m2[j]) ? q : amax[j];    // strict >: first max
                    m2[j] = fmaxf(m2[j], v[j]);
                    xt[j] = (q == tgs[j]) ? v[j] : xt[j];
                }
            }
        }

        if (tid < C) ts_local[tid] = 0u;
        __syncthreads();

        float ce = 0.f;
        unsigned nv = 0;
        #pragma unroll
        for (int j = 0; j < 2; ++j) {
            if (tgs[j] != 255) {
                ce += __logf(s[j]) - xt[j];
                nv++;
                atomicAdd(&counts[((size_t)b * Q + amax[j]) * C + tgs[j]], 1u);
                atomicAdd(&ts_local[tgs[j]], 1u);
            }
        }
        for (int off = 32; off; off >>= 1) {
            ce += __shfl_xor(ce, off);
            nv += __shfl_xor(nv, off);
        }
        if (lane == 0) { cred[wave] = ce; vred[wave] = nv; }
        __syncthreads();
        if (tid == 0) {
            atomicAdd(ce_sum, cred[0] + cred[1] + cred[2] + cred[3]);
            atomicAdd(n_valid, vred[0] + vred[1] + vred[2] + vred[3]);
        }
        if (tid < C) {
            unsigned t = ts_local[tid];
            if (t) atomicAdd(&tsum[b * C + tid], t);
        }
    }
}

// Kernel C: finalize. src_sum derived from inter_ext's 41 columns.
__global__ __launch_bounds__(512) void kC(const float* __restrict__ logits,
                                          const unsigned* __restrict__ counts,
                                          const unsigned* __restrict__ tsum,
                                          const float* __restrict__ inter_ext,
                                          const float* __restrict__ ce_sum,
                                          const unsigned* __restrict__ n_valid,
                                          float* __restrict__ out) {
    int tid = threadIdx.x;
    __shared__ float dice_sum[C];
    __shared__ float ssum[B * Q];
    __shared__ float wred[8];
    __shared__ float s_lce;
    if (tid < C) dice_sum[tid] = 0.f;
    if (tid < B * Q) {                     // src_sum[bq] = sum of all 41 cols
        const float* r = inter_ext + (size_t)tid * Cp1;
        float t = 0.f;
        #pragma unroll
        for (int c = 0; c < Cp1; ++c) t += r[c];
        ssum[tid] = t;
    }

    float ce_acc = 0.f;
    for (int i = tid; i < B * Q; i += 512) {
        const unsigned* cnt = counts + (size_t)i * C;
        unsigned best = 0;
        int tc = C;
        #pragma unroll
        for (int c = 0; c < C; ++c) {
            unsigned v = cnt[c];
            if (v > best) { best = v; tc = c; }
        }
        if (tc != C) {
            const float* lg = logits + (size_t)i * Cp1;
            float mm = -INFINITY, xt = 0.f;
            #pragma unroll
            for (int c = 0; c < Cp1; ++c) {
                float v = lg[c];
                mm = fmaxf(mm, v);
                if (c == tc) xt = v;
            }
            float ss = 0.f;
            #pragma unroll
            for (int c = 0; c < Cp1; ++c) ss += __expf(lg[c] - mm);
            float nll = mm + __logf(ss) - xt;
            float p = __expf(-nll);
            float om = 1.f - p;
            ce_acc += om * om * nll;
        }
    }
    for (int off = 32; off; off >>= 1) ce_acc += __shfl_xor(ce_acc, off);
    if ((tid & 63) == 0) wred[tid >> 6] = ce_acc;
    __syncthreads();                        // also publishes ssum + dice_sum init
    if (tid == 0) {
        float t = 0.f;
        for (int w = 0; w < 8; ++w) t += wred[w];
        s_lce = t;
    }

    for (int i = tid; i < B * Q * C; i += 512) {
        int bq = i / C, c = i - bq * C;
        float denom = ssum[bq] + (float)tsum[(bq / Q) * C + c] + 1e-8f;
        atomicAdd(&dice_sum[c], 2.f * inter_ext[(size_t)bq * Cp1 + c] / denom);
    }
    __syncthreads();

    if (tid == 0) {
        float dl = 0.f;
        for (int c = 0; c < C; ++c) {
            unsigned ts = tsum[c] + tsum[C + c] + tsum[2 * C + c] + tsum[3 * C + c];
            if (ts > 0) dl += 1.f - dice_sum[c] * (1.f / (B * Q));
        }
        dl *= (1.f / C);
        float ce_mask = ce_sum[0] / fmaxf((float)n_valid[0], 1.f);
        float lce = s_lce * (1.f / (B * Q));
        out[0] = 2.f * lce + 5.f * ce_mask + 5.f * dl;
    }
}

extern "C" void kernel_launch(void* const* d_in, const int* in_sizes, int n_in,
                              void* d_out, int out_size, void* d_ws, size_t ws_size,
                              hipStream_t stream) {
    const float* logits  = (const float*)d_in[0];   // [B,Q,41] f32
    const float* masks   = (const float*)d_in[1];   // [B,Q,H,W] f32
    const int*   targets = (const int*)d_in[2];     // [B,H,W] int32
    float* out = (float*)d_out;                     // f32 scalar

    unsigned* ws        = (unsigned*)d_ws;
    unsigned* counts    = ws;                       // 16000 u32
    unsigned* tsum      = ws + 16000;               // 160 u32
    float*    ce_sum    = (float*)(ws + 16160);     // 1 f32
    unsigned* n_valid   = ws + 16161;               // 1 u32
    float*    inter_ext = (float*)(ws + 16162);     // 16400 f32

    kZ<<<64, 256, 0, stream>>>(ws, WS_WORDS);
    kBig<<<GRID, 256, 0, stream>>>(masks, targets, counts, tsum, ce_sum, n_valid,
                                   inter_ext);
    kC<<<1, 512, 0, stream>>>(logits, counts, tsum, inter_ext, ce_sum, n_valid, out);
}

// Round 12
// 221.903 us; speedup vs baseline: 1.4140x; 1.0154x over previous
//
#include <hip/hip_runtime.h>
#include <hip/hip_bf16.h>

// Problem constants (fixed by setup_inputs)
constexpr int B = 4, Q = 100, C = 40, Cp1 = 41, HW = 65536;
constexpr int NPIX = B * HW;          // 262144

// B-part (MFMA one-hot GEMM): 7 q-tiles x 4 b = 28 rows, 128 K-segments of 512
constexpr int QT = 7;
constexpr int ROWS = B * QT;          // 28
constexpr int SEGS = 128;
constexpr int KSEG = HW / SEGS;       // 512
constexpr int BWAVES = ROWS * SEGS;   // 3584
constexpr int BBLK = BWAVES / 4;      // 896 blocks (4 waves each)

// A-part: 512 blocks, 256 thr, 2 px/thread (float2), 5-plane load batches
constexpr int ATHR = 256, APX = 2;
constexpr int ABLKS = NPIX / (ATHR * APX);   // 512
constexpr int ASLOT = HW / (ATHR * APX);     // 128
constexpr int QU = 5;

constexpr int GRID = BBLK + ABLKS;    // 1408 = 128 groups of 11 (4 A + 7 B)

// Workspace layout (4-byte words):
//  [0, 16000)        counts    u32 [B][Q][C]
//  [16000, 16160)    tsum      u32 [B][C]
//  [16160]           ce_sum    f32
//  [16161]           n_valid   u32
//  [16162, 32562)    inter_ext f32 [B*Q][41]   (col 40 = ignored-pixel sig sum)
constexpr int WS_WORDS = 32562;

typedef __attribute__((ext_vector_type(8))) short short8;   // 8 bf16
typedef __attribute__((ext_vector_type(4))) float f32x4;

__device__ __forceinline__ short f2bf(float f) {            // RNE f32->bf16
    unsigned u = __float_as_uint(f);
    u += 0x7FFF + ((u >> 16) & 1);
    return (short)(u >> 16);
}

__global__ void kZ(unsigned* __restrict__ ws, int n) {
    int i = blockIdx.x * blockDim.x + threadIdx.x;
    for (; i < n; i += gridDim.x * blockDim.x) ws[i] = 0u;
}

// ONE kernel, two independent phases. R12 change vs R11: phases are STRIPED
// through the block-index space (groups of 11 = 4 A-blocks + 7 B-blocks) so
// both are co-resident on every CU from t=0 — R11 dispatched all 896 B-blocks
// first, serializing the phases (t_A + t_B instead of max).
__global__ __launch_bounds__(256) void kBig(const float* __restrict__ masks,
                                            const int* __restrict__ targets,
                                            unsigned* __restrict__ counts,
                                            unsigned* __restrict__ tsum,
                                            float* __restrict__ ce_sum,
                                            unsigned* __restrict__ n_valid,
                                            float* __restrict__ inter_ext) {
    __shared__ float smem[4 * C];
    int tid = threadIdx.x;
    int blk = blockIdx.x;
    int lane = tid & 63, wave = tid >> 6;

    int grp = blk / 11, rem = blk - grp * 11;   // 128 groups x 11
    bool isA = rem < 4;

    if (!isA) {
        // ---------- B-part: MFMA one-hot GEMM (verified R11) ----------
        int bblk = grp * 7 + (rem - 4);  // 0..895
        int w = bblk * 4 + wave;         // 0..3583
        int row = w >> 7;                // /SEGS
        int seg = w & (SEGS - 1);
        int b = row / QT, qt = row - b * QT;
        int q0 = qt * 16;
        int k0 = seg * KSEG;
        int m = lane & 15, quad = lane >> 4;
        int qa = q0 + m; if (qa > 99) qa = 0;        // clamp (garbage rows unused)
        const float* ap = masks + ((size_t)b * Q + qa) * HW + k0 + quad * 8;
        const int*   tp = targets + (size_t)b * HW + k0 + quad * 8;
        int cv0 = m, cv1 = 16 + m;
        int cv2 = (m == 8) ? 255 : 32 + m;           // col 40 <- ignored pixels

        f32x4 acc0 = {0.f, 0.f, 0.f, 0.f};
        f32x4 acc1 = {0.f, 0.f, 0.f, 0.f};
        f32x4 acc2 = {0.f, 0.f, 0.f, 0.f};

        #pragma unroll 2
        for (int step = 0; step < KSEG / 32; ++step) {   // 16 steps
            int k = step * 32;
            float4 x0 = *(const float4*)(ap + k);
            float4 x1 = *(const float4*)(ap + k + 4);
            int4 t0 = *(const int4*)(tp + k);
            int4 t1 = *(const int4*)(tp + k + 4);
            float xs[8] = {x0.x, x0.y, x0.z, x0.w, x1.x, x1.y, x1.z, x1.w};
            int tss[8] = {t0.x, t0.y, t0.z, t0.w, t1.x, t1.y, t1.z, t1.w};
            short8 av, b0, b1, b2;
            #pragma unroll
            for (int j = 0; j < 8; ++j) {
                float sg = __builtin_amdgcn_rcpf(1.f + __expf(-xs[j]));
                av[j] = f2bf(sg);
                b0[j] = (tss[j] == cv0) ? (short)0x3F80 : (short)0;
                b1[j] = (tss[j] == cv1) ? (short)0x3F80 : (short)0;
                b2[j] = (tss[j] == cv2) ? (short)0x3F80 : (short)0;
            }
            acc0 = __builtin_amdgcn_mfma_f32_16x16x32_bf16(av, b0, acc0, 0, 0, 0);
            acc1 = __builtin_amdgcn_mfma_f32_16x16x32_bf16(av, b1, acc1, 0, 0, 0);
            acc2 = __builtin_amdgcn_mfma_f32_16x16x32_bf16(av, b2, acc2, 0, 0, 0);
        }

        // epilogue: D row = quad*4+reg, col = m (+ tile offset)
        #pragma unroll
        for (int reg = 0; reg < 4; ++reg) {
            int q = q0 + quad * 4 + reg;
            if (q < 100) {
                size_t base = (size_t)(b * Q + q) * Cp1;
                atomicAdd(&inter_ext[base + m], acc0[reg]);
                atomicAdd(&inter_ext[base + 16 + m], acc1[reg]);
                if (m <= 8) atomicAdd(&inter_ext[base + 32 + m], acc2[reg]);
            }
        }
    } else {
        // ---------- A-part: pixel-major (verified R8/R10/R11) ----------
        unsigned* ts_local = (unsigned*)&smem[0];
        float*    cred     = &smem[64];
        unsigned* vred     = (unsigned*)&smem[72];

        int ablk = grp * 4 + rem;        // 0..511
        int b = ablk / ASLOT;
        int hw = (ablk % ASLOT) * (ATHR * APX) + tid * APX;
        const float* mp = masks + (size_t)b * Q * HW + hw;
        int2 tg = *(const int2*)(targets + (size_t)b * HW + hw);
        int tgs[2] = {tg.x, tg.y};

        float m2[2] = {-INFINITY, -INFINITY}, s[2] = {0.f, 0.f}, xt[2] = {0.f, 0.f};
        int amax[2] = {0, 0};

        for (int qq = 0; qq < Q; qq += QU) {
            float2 vv[QU];
            #pragma unroll
            for (int u = 0; u < QU; ++u)
                vv[u] = *(const float2*)(mp + (size_t)(qq + u) * HW);
            #pragma unroll
            for (int u = 0; u < QU; ++u) {
                int q = qq + u;
                float v[2] = {vv[u].x, vv[u].y};
                #pragma unroll
                for (int j = 0; j < 2; ++j) {
                    s[j] += __expf(v[j]);                      // |v|<=~6: f32-safe
                    amax[j] = (v[j] > m2[j]) ? q : amax[j];    // strict >: first max
                    m2[j] = fmaxf(m2[j], v[j]);
                    xt[j] = (q == tgs[j]) ? v[j] : xt[j];
                }
            }
        }

        if (tid < C) ts_local[tid] = 0u;
        __syncthreads();

        float ce = 0.f;
        unsigned nv = 0;
        #pragma unroll
        for (int j = 0; j < 2; ++j) {
            if (tgs[j] != 255) {
                ce += __logf(s[j]) - xt[j];
                nv++;
                atomicAdd(&counts[((size_t)b * Q + amax[j]) * C + tgs[j]], 1u);
                atomicAdd(&ts_local[tgs[j]], 1u);
            }
        }
        for (int off = 32; off; off >>= 1) {
            ce += __shfl_xor(ce, off);
            nv += __shfl_xor(nv, off);
        }
        if (lane == 0) { cred[wave] = ce; vred[wave] = nv; }
        __syncthreads();
        if (tid == 0) {
            atomicAdd(ce_sum, cred[0] + cred[1] + cred[2] + cred[3]);
            atomicAdd(n_valid, vred[0] + vred[1] + vred[2] + vred[3]);
        }
        if (tid < C) {
            unsigned t = ts_local[tid];
            if (t) atomicAdd(&tsum[b * C + tid], t);
        }
    }
}

// Kernel C: finalize. src_sum derived from inter_ext's 41 columns. (Verified R11.)
__global__ __launch_bounds__(512) void kC(const float* __restrict__ logits,
                                          const unsigned* __restrict__ counts,
                                          const unsigned* __restrict__ tsum,
                                          const float* __restrict__ inter_ext,
                                          const float* __restrict__ ce_sum,
                                          const unsigned* __restrict__ n_valid,
                                          float* __restrict__ out) {
    int tid = threadIdx.x;
    __shared__ float dice_sum[C];
    __shared__ float ssum[B * Q];
    __shared__ float wred[8];
    __shared__ float s_lce;
    if (tid < C) dice_sum[tid] = 0.f;
    if (tid < B * Q) {                     // src_sum[bq] = sum of all 41 cols
        const float* r = inter_ext + (size_t)tid * Cp1;
        float t = 0.f;
        #pragma unroll
        for (int c = 0; c < Cp1; ++c) t += r[c];
        ssum[tid] = t;
    }

    float ce_acc = 0.f;
    for (int i = tid; i < B * Q; i += 512) {
        const unsigned* cnt = counts + (size_t)i * C;
        unsigned best = 0;
        int tc = C;
        #pragma unroll
        for (int c = 0; c < C; ++c) {
            unsigned v = cnt[c];
            if (v > best) { best = v; tc = c; }
        }
        if (tc != C) {
            const float* lg = logits + (size_t)i * Cp1;
            float mm = -INFINITY, xt = 0.f;
            #pragma unroll
            for (int c = 0; c < Cp1; ++c) {
                float v = lg[c];
                mm = fmaxf(mm, v);
                if (c == tc) xt = v;
            }
            float ss = 0.f;
            #pragma unroll
            for (int c = 0; c < Cp1; ++c) ss += __expf(lg[c] - mm);
            float nll = mm + __logf(ss) - xt;
            float p = __expf(-nll);
            float om = 1.f - p;
            ce_acc += om * om * nll;
        }
    }
    for (int off = 32; off; off >>= 1) ce_acc += __shfl_xor(ce_acc, off);
    if ((tid & 63) == 0) wred[tid >> 6] = ce_acc;
    __syncthreads();                        // also publishes ssum + dice_sum init
    if (tid == 0) {
        float t = 0.f;
        for (int w = 0; w < 8; ++w) t += wred[w];
        s_lce = t;
    }

    for (int i = tid; i < B * Q * C; i += 512) {
        int bq = i / C, c = i - bq * C;
        float denom = ssum[bq] + (float)tsum[(bq / Q) * C + c] + 1e-8f;
        atomicAdd(&dice_sum[c], 2.f * inter_ext[(size_t)bq * Cp1 + c] / denom);
    }
    __syncthreads();

    if (tid == 0) {
        float dl = 0.f;
        for (int c = 0; c < C; ++c) {
            unsigned ts = tsum[c] + tsum[C + c] + tsum[2 * C + c] + tsum[3 * C + c];
            if (ts > 0) dl += 1.f - dice_sum[c] * (1.f / (B * Q));
        }
        dl *= (1.f / C);
        float ce_mask = ce_sum[0] / fmaxf((float)n_valid[0], 1.f);
        float lce = s_lce * (1.f / (B * Q));
        out[0] = 2.f * lce + 5.f * ce_mask + 5.f * dl;
    }
}

extern "C" void kernel_launch(void* const* d_in, const int* in_sizes, int n_in,
                              void* d_out, int out_size, void* d_ws, size_t ws_size,
                              hipStream_t stream) {
    const float* logits  = (const float*)d_in[0];   // [B,Q,41] f32
    const float* masks   = (const float*)d_in[1];   // [B,Q,H,W] f32
    const int*   targets = (const int*)d_in[2];     // [B,H,W] int32
    float* out = (float*)d_out;                     // f32 scalar

    unsigned* ws        = (unsigned*)d_ws;
    unsigned* counts    = ws;                       // 16000 u32
    unsigned* tsum      = ws + 16000;               // 160 u32
    float*    ce_sum    = (float*)(ws + 16160);     // 1 f32
    unsigned* n_valid   = ws + 16161;               // 1 u32
    float*    inter_ext = (float*)(ws + 16162);     // 16400 f32

    kZ<<<64, 256, 0, stream>>>(ws, WS_WORDS);
    kBig<<<GRID, 256, 0, stream>>>(masks, targets, counts, tsum, ce_sum, n_valid,
                                   inter_ext);
    kC<<<1, 512, 0, stream>>>(logits, counts, tsum, inter_ext, ce_sum, n_valid, out);
}